// Round 3
// baseline (110.291 us; speedup 1.0000x reference)
//
#include <hip/hip_runtime.h>
#include <hip/hip_bf16.h>
#include <math.h>

#define B_PAIRS 2048
#define N_ROWS  4096
#define D_DIM   256
#define INV_T   2.0f

typedef __attribute__((ext_vector_type(8))) short  short8;   // 8 x bf16
typedef __attribute__((ext_vector_type(4))) float  floatx4;

// ---- workspace layout ----
// [0, 2MB)        : zn (bf16, 4096 x 256)
// [2MB, +16KB)    : S[4096]  (fp32, sum_{j!=i} exp(sim_ij))
// then            : posSum (fp32), cnt (u32)

__device__ __forceinline__ void async_copy16(const void* gsrc, void* ldst) {
    __builtin_amdgcn_global_load_lds(
        (__attribute__((address_space(1))) void*)gsrc,
        (__attribute__((address_space(3))) void*)ldst,
        16, 0, 0);
}

// ---------- kernel 1: row-normalize fp32 -> bf16 (1 wave per row) ----------
// Also zero-inits S[row], posSum, cnt (replaces memset dispatches).
__global__ __launch_bounds__(256)
void ntx_normalize(const float* __restrict__ z_i,
                   const float* __restrict__ z_j,
                   __hip_bfloat16* __restrict__ zn,
                   float* __restrict__ S,
                   float* __restrict__ posSum,
                   unsigned* __restrict__ cnt) {
    const int w    = threadIdx.x >> 6;               // wave 0..3
    const int lane = threadIdx.x & 63;
    const int row  = blockIdx.x * 4 + w;             // 0..4095
    const float* src = (row < B_PAIRS) ? (z_i + (size_t)row * D_DIM)
                                       : (z_j + (size_t)(row - B_PAIRS) * D_DIM);
    const float4 v = *(const float4*)(src + lane * 4);
    float ss = v.x * v.x + v.y * v.y + v.z * v.z + v.w * v.w;
    #pragma unroll
    for (int off = 32; off > 0; off >>= 1) ss += __shfl_xor(ss, off, 64);
    const float rn = 1.0f / fmaxf(sqrtf(ss), 1e-8f);
    union { short4 s4; __hip_bfloat16 h[4]; } u;
    u.h[0] = __float2bfloat16(v.x * rn);
    u.h[1] = __float2bfloat16(v.y * rn);
    u.h[2] = __float2bfloat16(v.z * rn);
    u.h[3] = __float2bfloat16(v.w * rn);
    *(short4*)(void*)(zn + (size_t)row * D_DIM + lane * 4) = u.s4;
    if (lane == 0) S[row] = 0.0f;
    if (blockIdx.x == 0 && threadIdx.x == 0) { *posSum = 0.0f; *cnt = 0u; }
}

// ---------- kernel 2: upper-triangle sim tiles + epilogue + fused finalize ----
#define BM 128
#define BN 128
#define BK 32
#define N_TILES 528            // 32 diag + 496 strictly-upper (32x32 tile grid)

__global__ __launch_bounds__(256)
void ntx_simtile(const __hip_bfloat16* __restrict__ zn,
                 float* __restrict__ S,
                 float* __restrict__ posSum,
                 unsigned* __restrict__ cnt,
                 float* __restrict__ out) {
    __shared__ __align__(16) __hip_bfloat16 As[BM * BK];
    __shared__ __align__(16) __hip_bfloat16 Bs[BN * BK];

    // linear block id -> upper-triangle (by, bx), bx >= by
    int t = blockIdx.x, by = 0, rowlen = 32;
    while (t >= rowlen) { t -= rowlen; by++; rowlen--; }
    const int bx = by + t;

    const int tid  = threadIdx.x;
    const int lane = tid & 63;
    const int w    = tid >> 6;           // wave 0..3
    const int wr   = w >> 1;             // wave row strip (0..1)
    const int wc   = w & 1;              // wave col strip (0..1)
    const int quad = lane >> 4;          // 0..3
    const int l16  = lane & 15;

    const int rowA0 = by * BM;
    const int rowB0 = bx * BN;
    const bool isDiag = (rowA0 == rowB0);
    const bool isPos  = (rowB0 == (rowA0 ^ B_PAIRS));

    floatx4 acc[4][4];
    #pragma unroll
    for (int i = 0; i < 4; i++)
        #pragma unroll
        for (int j = 0; j < 4; j++)
            acc[i][j] = (floatx4){0.f, 0.f, 0.f, 0.f};

    for (int k0 = 0; k0 < D_DIM; k0 += BK) {
        // Stage with XOR-swizzled SOURCE chunks: LDS slot (r,kc) holds global
        // chunk kc ^ ((r>>1)&3). LDS dest stays wave-uniform-base + lane*16
        // (global_load_lds constraint); only the global address is permuted.
        #pragma unroll
        for (int c = 0; c < 2; c++) {
            const int chunk = tid + c * 256;     // 0..511
            const int r  = chunk >> 2;           // tile row 0..127
            const int kc = chunk & 3;            // 16B slot within row
            const int g  = kc ^ ((r >> 1) & 3);  // swizzled global chunk
            async_copy16(zn + ((size_t)(rowA0 + r) * D_DIM + k0 + g * 8),
                         As + chunk * 8);
            async_copy16(zn + ((size_t)(rowB0 + r) * D_DIM + k0 + g * 8),
                         Bs + chunk * 8);
        }
        __syncthreads();

        // Fragment reads: undo the swizzle; start banks now spread over all
        // 8 disjoint b128 spans -> 2 lanes/span = conflict-free (m136).
        short8 afr[4], bfr[4];
        #pragma unroll
        for (int fi = 0; fi < 4; fi++) {
            const int ar = wr * 64 + fi * 16 + l16;
            const int sk = quad ^ ((ar >> 1) & 3);
            afr[fi] = *(const short8*)(const void*)(As + ar * BK + sk * 8);
        }
        #pragma unroll
        for (int fj = 0; fj < 4; fj++) {
            const int br = wc * 64 + fj * 16 + l16;
            const int sk = quad ^ ((br >> 1) & 3);
            bfr[fj] = *(const short8*)(const void*)(Bs + br * BK + sk * 8);
        }
        #pragma unroll
        for (int fi = 0; fi < 4; fi++)
            #pragma unroll
            for (int fj = 0; fj < 4; fj++)
                acc[fi][fj] = __builtin_amdgcn_mfma_f32_16x16x32_bf16(
                    afr[fi], bfr[fj], acc[fi][fj], 0, 0, 0);
        __syncthreads();
    }

    // Epilogue. C/D layout (16x16): col = l16, row = quad*4 + reg.
    // Row sums -> S[rowA0+ri]; off-diag tiles also col-sum -> S[rowB0+rj].
    // Positive pairs contribute 2*v to the scalar posSum (loss needs only Σpos).
    float cs[4] = {0.f, 0.f, 0.f, 0.f};
    float psum = 0.f;
    #pragma unroll
    for (int fi = 0; fi < 4; fi++) {
        float rs[4] = {0.f, 0.f, 0.f, 0.f};
        #pragma unroll
        for (int fj = 0; fj < 4; fj++) {
            const int rj = wc * 64 + fj * 16 + l16;
            #pragma unroll
            for (int reg = 0; reg < 4; reg++) {
                const int ri = wr * 64 + fi * 16 + quad * 4 + reg;
                const float v = acc[fi][fj][reg] * INV_T;
                const bool d = (ri == rj);
                if (isPos && d) psum += 2.0f * v;
                const float e = (isDiag && d) ? 0.f : __expf(v);
                rs[reg] += e;
                cs[fj]  += e;
            }
        }
        #pragma unroll
        for (int reg = 0; reg < 4; reg++) {
            float r = rs[reg];
            r += __shfl_xor(r, 1, 16);
            r += __shfl_xor(r, 2, 16);
            r += __shfl_xor(r, 4, 16);
            r += __shfl_xor(r, 8, 16);
            if (l16 == 0)
                atomicAdd(&S[rowA0 + wr * 64 + fi * 16 + quad * 4 + reg], r);
        }
    }
    if (!isDiag) {
        #pragma unroll
        for (int fj = 0; fj < 4; fj++) {
            float c = cs[fj];
            c += __shfl_xor(c, 16, 64);
            c += __shfl_xor(c, 32, 64);
            if (quad == 0)
                atomicAdd(&S[rowB0 + wc * 64 + fj * 16 + l16], c);
        }
    }
    if (isPos) {
        psum += __shfl_xor(psum, 1, 64);  psum += __shfl_xor(psum, 2, 64);
        psum += __shfl_xor(psum, 4, 64);  psum += __shfl_xor(psum, 8, 64);
        psum += __shfl_xor(psum, 16, 64); psum += __shfl_xor(psum, 32, 64);
        __shared__ float pred[4];
        if (lane == 0) pred[w] = psum;
        __syncthreads();
        if (tid == 0)
            atomicAdd(posSum, pred[0] + pred[1] + pred[2] + pred[3]);
    }

    // ---- fused finalize: last block computes loss ----
    __shared__ bool amLast;
    __threadfence();
    if (tid == 0) {
        unsigned old = atomicAdd(cnt, 1u);
        amLast = (old == N_TILES - 1);
    }
    __syncthreads();
    if (amLast) {
        __threadfence();
        float acc2 = 0.f;
        for (int i = tid; i < N_ROWS; i += 256) {
            float s = __hip_atomic_load(&S[i], __ATOMIC_RELAXED,
                                        __HIP_MEMORY_SCOPE_AGENT);
            acc2 += __logf(s);
        }
        #pragma unroll
        for (int off = 32; off > 0; off >>= 1) acc2 += __shfl_xor(acc2, off, 64);
        __shared__ float red[4];
        if (lane == 0) red[w] = acc2;
        __syncthreads();
        if (tid == 0) {
            float logsum = red[0] + red[1] + red[2] + red[3];
            float ps = __hip_atomic_load(posSum, __ATOMIC_RELAXED,
                                         __HIP_MEMORY_SCOPE_AGENT);
            out[0] = (logsum - ps) / (float)N_ROWS;
        }
    }
}

extern "C" void kernel_launch(void* const* d_in, const int* in_sizes, int n_in,
                              void* d_out, int out_size, void* d_ws, size_t ws_size,
                              hipStream_t stream) {
    const float* z_i = (const float*)d_in[0];
    const float* z_j = (const float*)d_in[1];
    float* out = (float*)d_out;

    __hip_bfloat16* zn = (__hip_bfloat16*)d_ws;
    float* S        = (float*)((char*)d_ws + (size_t)N_ROWS * D_DIM * sizeof(__hip_bfloat16));
    float* posSum   = S + N_ROWS;
    unsigned* cnt   = (unsigned*)(posSum + 1);

    ntx_normalize<<<N_ROWS / 4, 256, 0, stream>>>(z_i, z_j, zn, S, posSum, cnt);
    ntx_simtile<<<N_TILES, 256, 0, stream>>>(zn, S, posSum, cnt, out);
}

// Round 4
// 89.006 us; speedup vs baseline: 1.2391x; 1.2391x over previous
//
#include <hip/hip_runtime.h>
#include <hip/hip_bf16.h>
#include <math.h>

#define B_PAIRS 2048
#define N_ROWS  4096
#define D_DIM   256
#define INV_T   2.0f

typedef __attribute__((ext_vector_type(8))) short  short8;   // 8 x bf16
typedef __attribute__((ext_vector_type(4))) float  floatx4;

// ---- workspace layout ----
// [0, 2MB)        : zn (bf16, 4096 x 256)
// [2MB, +16KB)    : S[4096]  (fp32, sum_{j!=i} exp(sim_ij))
// then            : posSum (fp32), cnt (u32)

__device__ __forceinline__ void async_copy16(const void* gsrc, void* ldst) {
    __builtin_amdgcn_global_load_lds(
        (__attribute__((address_space(1))) void*)gsrc,
        (__attribute__((address_space(3))) void*)ldst,
        16, 0, 0);
}

// ---------- kernel 1: row-normalize fp32 -> bf16 (1 wave per row) ----------
// Also zero-inits S[row], posSum, cnt.
__global__ __launch_bounds__(256)
void ntx_normalize(const float* __restrict__ z_i,
                   const float* __restrict__ z_j,
                   __hip_bfloat16* __restrict__ zn,
                   float* __restrict__ S,
                   float* __restrict__ posSum,
                   unsigned* __restrict__ cnt) {
    const int w    = threadIdx.x >> 6;               // wave 0..3
    const int lane = threadIdx.x & 63;
    const int row  = blockIdx.x * 4 + w;             // 0..4095
    const float* src = (row < B_PAIRS) ? (z_i + (size_t)row * D_DIM)
                                       : (z_j + (size_t)(row - B_PAIRS) * D_DIM);
    const float4 v = *(const float4*)(src + lane * 4);
    float ss = v.x * v.x + v.y * v.y + v.z * v.z + v.w * v.w;
    #pragma unroll
    for (int off = 32; off > 0; off >>= 1) ss += __shfl_xor(ss, off, 64);
    const float rn = 1.0f / fmaxf(sqrtf(ss), 1e-8f);
    union { short4 s4; __hip_bfloat16 h[4]; } u;
    u.h[0] = __float2bfloat16(v.x * rn);
    u.h[1] = __float2bfloat16(v.y * rn);
    u.h[2] = __float2bfloat16(v.z * rn);
    u.h[3] = __float2bfloat16(v.w * rn);
    *(short4*)(void*)(zn + (size_t)row * D_DIM + lane * 4) = u.s4;
    if (lane == 0) S[row] = 0.0f;
    if (blockIdx.x == 0 && threadIdx.x == 0) { *posSum = 0.0f; *cnt = 0u; }
}

// ---------- kernel 2: upper-triangle sim tiles + epilogue + fused finalize ----
#define BM 128
#define BN 128
#define BK 32
#define N_TILES 528            // 32 diag + 496 strictly-upper (32x32 tile grid)

__global__ __launch_bounds__(256)
void ntx_simtile(const __hip_bfloat16* __restrict__ zn,
                 float* __restrict__ S,
                 float* __restrict__ posSum,
                 unsigned* __restrict__ cnt,
                 float* __restrict__ out) {
    __shared__ __align__(16) __hip_bfloat16 As[BM * BK];
    __shared__ __align__(16) __hip_bfloat16 Bs[BN * BK];

    // linear block id -> upper-triangle (by, bx), bx >= by
    int t = blockIdx.x, by = 0, rowlen = 32;
    while (t >= rowlen) { t -= rowlen; by++; rowlen--; }
    const int bx = by + t;

    const int tid  = threadIdx.x;
    const int lane = tid & 63;
    const int w    = tid >> 6;           // wave 0..3
    const int wr   = w >> 1;             // wave row strip (0..1)
    const int wc   = w & 1;              // wave col strip (0..1)
    const int quad = lane >> 4;          // 0..3
    const int l16  = lane & 15;

    const int rowA0 = by * BM;
    const int rowB0 = bx * BN;
    const bool isDiag = (rowA0 == rowB0);
    const bool isPos  = (rowB0 == (rowA0 ^ B_PAIRS));

    floatx4 acc[4][4];
    #pragma unroll
    for (int i = 0; i < 4; i++)
        #pragma unroll
        for (int j = 0; j < 4; j++)
            acc[i][j] = (floatx4){0.f, 0.f, 0.f, 0.f};

    for (int k0 = 0; k0 < D_DIM; k0 += BK) {
        // LINEAR staging (round-2 pattern): lane->address strictly linear so
        // global_load_lds coalesces. (Round-3 XOR-swizzle of the global side
        // tanked it ~4x: per-lane scatter defeats the direct-to-LDS burst.)
        #pragma unroll
        for (int c = 0; c < 2; c++) {
            const int chunk = tid + c * 256;     // 0..511
            const int r  = chunk >> 2;           // tile row 0..127
            const int kc = chunk & 3;            // 16B chunk within row
            async_copy16(zn + ((size_t)(rowA0 + r) * D_DIM + k0 + kc * 8),
                         As + chunk * 8);
            async_copy16(zn + ((size_t)(rowB0 + r) * D_DIM + k0 + kc * 8),
                         Bs + chunk * 8);
        }
        __syncthreads();

        short8 afr[4], bfr[4];
        #pragma unroll
        for (int fi = 0; fi < 4; fi++) {
            const int ar = wr * 64 + fi * 16 + l16;
            afr[fi] = *(const short8*)(const void*)(As + ar * BK + quad * 8);
        }
        #pragma unroll
        for (int fj = 0; fj < 4; fj++) {
            const int br = wc * 64 + fj * 16 + l16;
            bfr[fj] = *(const short8*)(const void*)(Bs + br * BK + quad * 8);
        }
        #pragma unroll
        for (int fi = 0; fi < 4; fi++)
            #pragma unroll
            for (int fj = 0; fj < 4; fj++)
                acc[fi][fj] = __builtin_amdgcn_mfma_f32_16x16x32_bf16(
                    afr[fi], bfr[fj], acc[fi][fj], 0, 0, 0);
        __syncthreads();
    }

    // Epilogue. C/D layout (16x16): col = l16, row = quad*4 + reg.
    // Row sums -> S[rowA0+ri]; off-diag tiles also col-sum -> S[rowB0+rj].
    // Positive pairs contribute 2*v to scalar posSum (loss needs only Σpos).
    float cs[4] = {0.f, 0.f, 0.f, 0.f};
    float psum = 0.f;
    #pragma unroll
    for (int fi = 0; fi < 4; fi++) {
        float rs[4] = {0.f, 0.f, 0.f, 0.f};
        #pragma unroll
        for (int fj = 0; fj < 4; fj++) {
            const int rj = wc * 64 + fj * 16 + l16;
            #pragma unroll
            for (int reg = 0; reg < 4; reg++) {
                const int ri = wr * 64 + fi * 16 + quad * 4 + reg;
                const float v = acc[fi][fj][reg] * INV_T;
                const bool d = (ri == rj);
                if (isPos && d) psum += 2.0f * v;
                const float e = (isDiag && d) ? 0.f : __expf(v);
                rs[reg] += e;
                cs[fj]  += e;
            }
        }
        #pragma unroll
        for (int reg = 0; reg < 4; reg++) {
            float r = rs[reg];
            r += __shfl_xor(r, 1, 16);
            r += __shfl_xor(r, 2, 16);
            r += __shfl_xor(r, 4, 16);
            r += __shfl_xor(r, 8, 16);
            if (l16 == 0)
                atomicAdd(&S[rowA0 + wr * 64 + fi * 16 + quad * 4 + reg], r);
        }
    }
    if (!isDiag) {
        #pragma unroll
        for (int fj = 0; fj < 4; fj++) {
            float c = cs[fj];
            c += __shfl_xor(c, 16, 64);
            c += __shfl_xor(c, 32, 64);
            if (quad == 0)
                atomicAdd(&S[rowB0 + wc * 64 + fj * 16 + l16], c);
        }
    }
    if (isPos) {
        psum += __shfl_xor(psum, 1, 64);  psum += __shfl_xor(psum, 2, 64);
        psum += __shfl_xor(psum, 4, 64);  psum += __shfl_xor(psum, 8, 64);
        psum += __shfl_xor(psum, 16, 64); psum += __shfl_xor(psum, 32, 64);
        __shared__ float pred[4];
        if (lane == 0) pred[w] = psum;
        __syncthreads();
        if (tid == 0)
            atomicAdd(posSum, pred[0] + pred[1] + pred[2] + pred[3]);
    }

    // ---- fused finalize: last block computes loss ----
    // __syncthreads()'s vmcnt(0)-drain orders the block's S/posSum atomics;
    // a single ACQ_REL RMW by tid 0 (agent scope) publishes + pairs with the
    // last block's reads. NO all-thread __threadfence (round-3 cost).
    __shared__ bool amLast;
    __syncthreads();
    if (tid == 0) {
        unsigned old = __hip_atomic_fetch_add(cnt, 1u, __ATOMIC_ACQ_REL,
                                              __HIP_MEMORY_SCOPE_AGENT);
        amLast = (old == N_TILES - 1);
    }
    __syncthreads();
    if (amLast) {
        float acc2 = 0.f;
        for (int i = tid; i < N_ROWS; i += 256) {
            float s = __hip_atomic_load(&S[i], __ATOMIC_RELAXED,
                                        __HIP_MEMORY_SCOPE_AGENT);
            acc2 += __logf(s);
        }
        #pragma unroll
        for (int off = 32; off > 0; off >>= 1) acc2 += __shfl_xor(acc2, off, 64);
        __shared__ float red[4];
        if (lane == 0) red[w] = acc2;
        __syncthreads();
        if (tid == 0) {
            float logsum = red[0] + red[1] + red[2] + red[3];
            float ps = __hip_atomic_load(posSum, __ATOMIC_RELAXED,
                                         __HIP_MEMORY_SCOPE_AGENT);
            out[0] = (logsum - ps) / (float)N_ROWS;
        }
    }
}

extern "C" void kernel_launch(void* const* d_in, const int* in_sizes, int n_in,
                              void* d_out, int out_size, void* d_ws, size_t ws_size,
                              hipStream_t stream) {
    const float* z_i = (const float*)d_in[0];
    const float* z_j = (const float*)d_in[1];
    float* out = (float*)d_out;

    __hip_bfloat16* zn = (__hip_bfloat16*)d_ws;
    float* S        = (float*)((char*)d_ws + (size_t)N_ROWS * D_DIM * sizeof(__hip_bfloat16));
    float* posSum   = S + N_ROWS;
    unsigned* cnt   = (unsigned*)(posSum + 1);

    ntx_normalize<<<N_ROWS / 4, 256, 0, stream>>>(z_i, z_j, zn, S, posSum, cnt);
    ntx_simtile<<<N_TILES, 256, 0, stream>>>(zn, S, posSum, cnt, out);
}

// Round 5
// 81.010 us; speedup vs baseline: 1.3614x; 1.0987x over previous
//
#include <hip/hip_runtime.h>
#include <hip/hip_bf16.h>
#include <math.h>

#define B_PAIRS 2048
#define N_ROWS  4096
#define D_DIM   256
#define INV_T   2.0f

typedef __attribute__((ext_vector_type(8))) short  short8;   // 8 x bf16
typedef __attribute__((ext_vector_type(4))) float  floatx4;

// ---- workspace layout ----
// [0, 2MB)        : zn (bf16, 4096 x 256)
// [2MB, +16KB)    : S[4096]  (fp32, sum_{j!=i} exp(sim_ij))
// then            : posSum (fp32)

__device__ __forceinline__ void async_copy16(const void* gsrc, void* ldst) {
    __builtin_amdgcn_global_load_lds(
        (__attribute__((address_space(1))) void*)gsrc,
        (__attribute__((address_space(3))) void*)ldst,
        16, 0, 0);
}

// ---------- kernel 1: row-normalize fp32 -> bf16 (1 wave per row) ----------
// Also zero-inits S[row] and posSum.
__global__ __launch_bounds__(256)
void ntx_normalize(const float* __restrict__ z_i,
                   const float* __restrict__ z_j,
                   __hip_bfloat16* __restrict__ zn,
                   float* __restrict__ S,
                   float* __restrict__ posSum) {
    const int w    = threadIdx.x >> 6;               // wave 0..3
    const int lane = threadIdx.x & 63;
    const int row  = blockIdx.x * 4 + w;             // 0..4095
    const float* src = (row < B_PAIRS) ? (z_i + (size_t)row * D_DIM)
                                       : (z_j + (size_t)(row - B_PAIRS) * D_DIM);
    const float4 v = *(const float4*)(src + lane * 4);
    float ss = v.x * v.x + v.y * v.y + v.z * v.z + v.w * v.w;
    #pragma unroll
    for (int off = 32; off > 0; off >>= 1) ss += __shfl_xor(ss, off, 64);
    const float rn = 1.0f / fmaxf(sqrtf(ss), 1e-8f);
    union { short4 s4; __hip_bfloat16 h[4]; } u;
    u.h[0] = __float2bfloat16(v.x * rn);
    u.h[1] = __float2bfloat16(v.y * rn);
    u.h[2] = __float2bfloat16(v.z * rn);
    u.h[3] = __float2bfloat16(v.w * rn);
    *(short4*)(void*)(zn + (size_t)row * D_DIM + lane * 4) = u.s4;
    if (lane == 0) S[row] = 0.0f;
    if (blockIdx.x == 0 && threadIdx.x == 0) *posSum = 0.0f;
}

// ---------- kernel 2: upper-triangle sim tiles + exp row/col-sum epilogue ----
#define BM 128
#define BN 128
#define BK 32
#define N_TILES 528            // 32 diag + 496 strictly-upper (32x32 tile grid)

__global__ __launch_bounds__(256)
void ntx_simtile(const __hip_bfloat16* __restrict__ zn,
                 float* __restrict__ S,
                 float* __restrict__ posSum) {
    __shared__ __align__(16) __hip_bfloat16 As[BM * BK];
    __shared__ __align__(16) __hip_bfloat16 Bs[BN * BK];

    // linear block id -> upper-triangle (by, bx), bx >= by
    int t = blockIdx.x, by = 0, rowlen = 32;
    while (t >= rowlen) { t -= rowlen; by++; rowlen--; }
    const int bx = by + t;

    const int tid  = threadIdx.x;
    const int lane = tid & 63;
    const int w    = tid >> 6;           // wave 0..3
    const int wr   = w >> 1;             // wave row strip (0..1)
    const int wc   = w & 1;              // wave col strip (0..1)
    const int quad = lane >> 4;          // 0..3
    const int l16  = lane & 15;

    const int rowA0 = by * BM;
    const int rowB0 = bx * BN;
    const bool isDiag = (rowA0 == rowB0);
    const bool isPos  = (rowB0 == (rowA0 ^ B_PAIRS));

    floatx4 acc[4][4];
    #pragma unroll
    for (int i = 0; i < 4; i++)
        #pragma unroll
        for (int j = 0; j < 4; j++)
            acc[i][j] = (floatx4){0.f, 0.f, 0.f, 0.f};

    for (int k0 = 0; k0 < D_DIM; k0 += BK) {
        // LINEAR staging: lane->address strictly linear so global_load_lds
        // coalesces (round-3 global-side XOR swizzle cost ~4x — never again).
        #pragma unroll
        for (int c = 0; c < 2; c++) {
            const int chunk = tid + c * 256;     // 0..511
            const int r  = chunk >> 2;           // tile row 0..127
            const int kc = chunk & 3;            // 16B chunk within row
            async_copy16(zn + ((size_t)(rowA0 + r) * D_DIM + k0 + kc * 8),
                         As + chunk * 8);
            async_copy16(zn + ((size_t)(rowB0 + r) * D_DIM + k0 + kc * 8),
                         Bs + chunk * 8);
        }
        __syncthreads();

        short8 afr[4], bfr[4];
        #pragma unroll
        for (int fi = 0; fi < 4; fi++) {
            const int ar = wr * 64 + fi * 16 + l16;
            afr[fi] = *(const short8*)(const void*)(As + ar * BK + quad * 8);
        }
        #pragma unroll
        for (int fj = 0; fj < 4; fj++) {
            const int br = wc * 64 + fj * 16 + l16;
            bfr[fj] = *(const short8*)(const void*)(Bs + br * BK + quad * 8);
        }
        #pragma unroll
        for (int fi = 0; fi < 4; fi++)
            #pragma unroll
            for (int fj = 0; fj < 4; fj++)
                acc[fi][fj] = __builtin_amdgcn_mfma_f32_16x16x32_bf16(
                    afr[fi], bfr[fj], acc[fi][fj], 0, 0, 0);
        __syncthreads();
    }

    // Epilogue. C/D layout (16x16): col = l16, row = quad*4 + reg.
    // Row sums -> S[rowA0+ri]; off-diag tiles also col-sum -> S[rowB0+rj]
    // (symmetry). Positive pairs contribute 2*v to scalar posSum.
    float cs[4] = {0.f, 0.f, 0.f, 0.f};
    float psum = 0.f;
    #pragma unroll
    for (int fi = 0; fi < 4; fi++) {
        float rs[4] = {0.f, 0.f, 0.f, 0.f};
        #pragma unroll
        for (int fj = 0; fj < 4; fj++) {
            const int rj = wc * 64 + fj * 16 + l16;
            #pragma unroll
            for (int reg = 0; reg < 4; reg++) {
                const int ri = wr * 64 + fi * 16 + quad * 4 + reg;
                const float v = acc[fi][fj][reg] * INV_T;
                const bool d = (ri == rj);
                if (isPos && d) psum += 2.0f * v;
                const float e = (isDiag && d) ? 0.f : __expf(v);
                rs[reg] += e;
                cs[fj]  += e;
            }
        }
        #pragma unroll
        for (int reg = 0; reg < 4; reg++) {
            float r = rs[reg];
            r += __shfl_xor(r, 1, 16);
            r += __shfl_xor(r, 2, 16);
            r += __shfl_xor(r, 4, 16);
            r += __shfl_xor(r, 8, 16);
            if (l16 == 0)
                atomicAdd(&S[rowA0 + wr * 64 + fi * 16 + quad * 4 + reg], r);
        }
    }
    if (!isDiag) {
        #pragma unroll
        for (int fj = 0; fj < 4; fj++) {
            float c = cs[fj];
            c += __shfl_xor(c, 16, 64);
            c += __shfl_xor(c, 32, 64);
            if (quad == 0)
                atomicAdd(&S[rowB0 + wc * 64 + fj * 16 + l16], c);
        }
    }
    if (isPos) {
        psum += __shfl_xor(psum, 1, 64);  psum += __shfl_xor(psum, 2, 64);
        psum += __shfl_xor(psum, 4, 64);  psum += __shfl_xor(psum, 8, 64);
        psum += __shfl_xor(psum, 16, 64); psum += __shfl_xor(psum, 32, 64);
        __shared__ float pred[4];
        if (lane == 0) pred[w] = psum;
        __syncthreads();
        if (tid == 0)
            atomicAdd(posSum, pred[0] + pred[1] + pred[2] + pred[3]);
    }
}

// ---------- kernel 3: loss = (sum log S_i - posSum) / N ----------
__global__ __launch_bounds__(1024)
void ntx_finalize(const float* __restrict__ S,
                  const float* __restrict__ posSum,
                  float* __restrict__ out) {
    const int tid = threadIdx.x;   // 1024 threads
    float acc = 0.f;
    #pragma unroll
    for (int c = 0; c < 4; c++)
        acc += __logf(S[tid + c * 1024]);
    #pragma unroll
    for (int off = 32; off > 0; off >>= 1) acc += __shfl_xor(acc, off, 64);
    __shared__ float red[16];
    if ((tid & 63) == 0) red[tid >> 6] = acc;
    __syncthreads();
    if (tid == 0) {
        float s = 0.f;
        #pragma unroll
        for (int k = 0; k < 16; k++) s += red[k];
        out[0] = (s - *posSum) / (float)N_ROWS;
    }
}

extern "C" void kernel_launch(void* const* d_in, const int* in_sizes, int n_in,
                              void* d_out, int out_size, void* d_ws, size_t ws_size,
                              hipStream_t stream) {
    const float* z_i = (const float*)d_in[0];
    const float* z_j = (const float*)d_in[1];
    float* out = (float*)d_out;

    __hip_bfloat16* zn = (__hip_bfloat16*)d_ws;
    float* S      = (float*)((char*)d_ws + (size_t)N_ROWS * D_DIM * sizeof(__hip_bfloat16));
    float* posSum = S + N_ROWS;

    ntx_normalize<<<N_ROWS / 4, 256, 0, stream>>>(z_i, z_j, zn, S, posSum);
    ntx_simtile<<<N_TILES, 256, 0, stream>>>(zn, S, posSum);
    ntx_finalize<<<1, 1024, 0, stream>>>(S, posSum, out);
}

// Round 6
// 80.715 us; speedup vs baseline: 1.3664x; 1.0037x over previous
//
#include <hip/hip_runtime.h>
#include <hip/hip_bf16.h>
#include <math.h>

#define B_PAIRS 2048
#define N_ROWS  4096
#define D_DIM   256
#define INV_T   2.0f

typedef __attribute__((ext_vector_type(4))) float  floatx4;

// ---- workspace layout ----
// [0, 1MB)        : zn8 (fp8 e4m3, 4096 x 256)
// [1MB, +16KB)    : S[4096]  (fp32, sum_{j!=i} exp(sim_ij))
// then            : posSum (fp32)

__device__ __forceinline__ void async_copy16(const void* gsrc, void* ldst) {
    __builtin_amdgcn_global_load_lds(
        (__attribute__((address_space(1))) void*)gsrc,
        (__attribute__((address_space(3))) void*)ldst,
        16, 0, 0);
}

// ---------- kernel 1: row-normalize fp32 -> fp8 e4m3 (1 wave per row) -------
// Also zero-inits S[row] and posSum.
__global__ __launch_bounds__(256)
void ntx_normalize(const float* __restrict__ z_i,
                   const float* __restrict__ z_j,
                   unsigned* __restrict__ zn8,   // 4096 x 64 packed fp8x4
                   float* __restrict__ S,
                   float* __restrict__ posSum) {
    const int w    = threadIdx.x >> 6;               // wave 0..3
    const int lane = threadIdx.x & 63;
    const int row  = blockIdx.x * 4 + w;             // 0..4095
    const float* src = (row < B_PAIRS) ? (z_i + (size_t)row * D_DIM)
                                       : (z_j + (size_t)(row - B_PAIRS) * D_DIM);
    const float4 v = *(const float4*)(src + lane * 4);
    float ss = v.x * v.x + v.y * v.y + v.z * v.z + v.w * v.w;
    #pragma unroll
    for (int off = 32; off > 0; off >>= 1) ss += __shfl_xor(ss, off, 64);
    const float rn = 1.0f / fmaxf(sqrtf(ss), 1e-8f);
    unsigned pk = 0;
    pk = __builtin_amdgcn_cvt_pk_fp8_f32(v.x * rn, v.y * rn, pk, false);
    pk = __builtin_amdgcn_cvt_pk_fp8_f32(v.z * rn, v.w * rn, pk, true);
    zn8[(size_t)row * (D_DIM / 4) + lane] = pk;
    if (lane == 0) S[row] = 0.0f;
    if (blockIdx.x == 0 && threadIdx.x == 0) *posSum = 0.0f;
}

// ---------- kernel 2: upper-triangle sim tiles (fp8 MFMA) + epilogue --------
#define BM 128
#define BN 128
#define BK 32                  // 32 fp8 elements = 32 bytes per row per iter
#define N_TILES 528            // 32 diag + 496 strictly-upper (32x32 tile grid)

__global__ __launch_bounds__(256)
void ntx_simtile(const unsigned char* __restrict__ zn8,
                 float* __restrict__ S,
                 float* __restrict__ posSum) {
    __shared__ __align__(16) unsigned char As[BM * BK];   // 4 KB
    __shared__ __align__(16) unsigned char Bs[BN * BK];   // 4 KB

    // linear block id -> upper-triangle (by, bx), bx >= by
    int t = blockIdx.x, by = 0, rowlen = 32;
    while (t >= rowlen) { t -= rowlen; by++; rowlen--; }
    const int bx = by + t;

    const int tid  = threadIdx.x;
    const int lane = tid & 63;
    const int w    = tid >> 6;           // wave 0..3
    const int wr   = w >> 1;             // wave row strip (0..1)
    const int wc   = w & 1;              // wave col strip (0..1)
    const int quad = lane >> 4;          // 0..3
    const int l16  = lane & 15;

    const int rowA0 = by * BM;
    const int rowB0 = bx * BN;
    const bool isDiag = (rowA0 == rowB0);
    const bool isPos  = (rowB0 == (rowA0 ^ B_PAIRS));

    floatx4 acc[4][4];
    #pragma unroll
    for (int i = 0; i < 4; i++)
        #pragma unroll
        for (int j = 0; j < 4; j++)
            acc[i][j] = (floatx4){0.f, 0.f, 0.f, 0.f};

    for (int k0 = 0; k0 < D_DIM; k0 += BK) {   // k0 in elements == bytes (fp8)
        // LINEAR staging: 128 rows x 32 B = 256 chunks of 16 B; one per thread.
        const int r  = tid >> 1;             // tile row 0..127
        const int kc = tid & 1;              // 16B chunk within row
        async_copy16(zn8 + ((size_t)(rowA0 + r) * D_DIM + k0 + kc * 16),
                     As + tid * 16);
        async_copy16(zn8 + ((size_t)(rowB0 + r) * D_DIM + k0 + kc * 16),
                     Bs + tid * 16);
        __syncthreads();

        // Fragments: 8 fp8/lane = 8 B; A[m=l16][k=quad*8+j], row stride 32 B.
        long afr[4], bfr[4];
        #pragma unroll
        for (int fi = 0; fi < 4; fi++) {
            const int ar = wr * 64 + fi * 16 + l16;
            afr[fi] = *(const long*)(const void*)(As + ar * BK + quad * 8);
        }
        #pragma unroll
        for (int fj = 0; fj < 4; fj++) {
            const int br = wc * 64 + fj * 16 + l16;
            bfr[fj] = *(const long*)(const void*)(Bs + br * BK + quad * 8);
        }
        #pragma unroll
        for (int fi = 0; fi < 4; fi++)
            #pragma unroll
            for (int fj = 0; fj < 4; fj++)
                acc[fi][fj] = __builtin_amdgcn_mfma_f32_16x16x32_fp8_fp8(
                    afr[fi], bfr[fj], acc[fi][fj], 0, 0, 0);
        __syncthreads();
    }

    // Epilogue. C/D layout (16x16, dtype-independent): col = l16, row = quad*4+reg.
    // Row sums -> S[rowA0+ri]; off-diag tiles also col-sum -> S[rowB0+rj]
    // (symmetry). Positive pairs contribute 2*v to scalar posSum.
    float cs[4] = {0.f, 0.f, 0.f, 0.f};
    float psum = 0.f;
    #pragma unroll
    for (int fi = 0; fi < 4; fi++) {
        float rs[4] = {0.f, 0.f, 0.f, 0.f};
        #pragma unroll
        for (int fj = 0; fj < 4; fj++) {
            const int rj = wc * 64 + fj * 16 + l16;
            #pragma unroll
            for (int reg = 0; reg < 4; reg++) {
                const int ri = wr * 64 + fi * 16 + quad * 4 + reg;
                const float v = acc[fi][fj][reg] * INV_T;
                const bool d = (ri == rj);
                if (isPos && d) psum += 2.0f * v;
                const float e = (isDiag && d) ? 0.f : __expf(v);
                rs[reg] += e;
                cs[fj]  += e;
            }
        }
        #pragma unroll
        for (int reg = 0; reg < 4; reg++) {
            float r = rs[reg];
            r += __shfl_xor(r, 1, 16);
            r += __shfl_xor(r, 2, 16);
            r += __shfl_xor(r, 4, 16);
            r += __shfl_xor(r, 8, 16);
            if (l16 == 0)
                atomicAdd(&S[rowA0 + wr * 64 + fi * 16 + quad * 4 + reg], r);
        }
    }
    if (!isDiag) {
        #pragma unroll
        for (int fj = 0; fj < 4; fj++) {
            float c = cs[fj];
            c += __shfl_xor(c, 16, 64);
            c += __shfl_xor(c, 32, 64);
            if (quad == 0)
                atomicAdd(&S[rowB0 + wc * 64 + fj * 16 + l16], c);
        }
    }
    if (isPos) {
        psum += __shfl_xor(psum, 1, 64);  psum += __shfl_xor(psum, 2, 64);
        psum += __shfl_xor(psum, 4, 64);  psum += __shfl_xor(psum, 8, 64);
        psum += __shfl_xor(psum, 16, 64); psum += __shfl_xor(psum, 32, 64);
        __shared__ float pred[4];
        if (lane == 0) pred[w] = psum;
        __syncthreads();
        if (tid == 0)
            atomicAdd(posSum, pred[0] + pred[1] + pred[2] + pred[3]);
    }
}

// ---------- kernel 3: loss = (sum log S_i - posSum) / N ----------
__global__ __launch_bounds__(1024)
void ntx_finalize(const float* __restrict__ S,
                  const float* __restrict__ posSum,
                  float* __restrict__ out) {
    const int tid = threadIdx.x;   // 1024 threads
    float acc = 0.f;
    #pragma unroll
    for (int c = 0; c < 4; c++)
        acc += __logf(S[tid + c * 1024]);
    #pragma unroll
    for (int off = 32; off > 0; off >>= 1) acc += __shfl_xor(acc, off, 64);
    __shared__ float red[16];
    if ((tid & 63) == 0) red[tid >> 6] = acc;
    __syncthreads();
    if (tid == 0) {
        float s = 0.f;
        #pragma unroll
        for (int k = 0; k < 16; k++) s += red[k];
        out[0] = (s - *posSum) / (float)N_ROWS;
    }
}

extern "C" void kernel_launch(void* const* d_in, const int* in_sizes, int n_in,
                              void* d_out, int out_size, void* d_ws, size_t ws_size,
                              hipStream_t stream) {
    const float* z_i = (const float*)d_in[0];
    const float* z_j = (const float*)d_in[1];
    float* out = (float*)d_out;

    unsigned char* zn8 = (unsigned char*)d_ws;
    float* S      = (float*)((char*)d_ws + (size_t)N_ROWS * D_DIM);  // 1 MB
    float* posSum = S + N_ROWS;

    ntx_normalize<<<N_ROWS / 4, 256, 0, stream>>>(z_i, z_j, (unsigned*)zn8, S, posSum);
    ntx_simtile<<<N_TILES, 256, 0, stream>>>(zn8, S, posSum);
    ntx_finalize<<<1, 1024, 0, stream>>>(S, posSum, out);
}